// Round 1
// baseline (5291.157 us; speedup 1.0000x reference)
//
#include <hip/hip_runtime.h>
#include <math.h>

// Shapes: B=512, N=196 (14x14), C=512, NH=8, HD=64, AGENT=49 (7x7)
// Layouts in workspace:
//   q_h : (b,h,n,d)   plane 196*64=12544 per bh
//   k_t : (b,h,d,n)   TRANSPOSED, plane 12544   (aliased later as attn_out (b,n,c))
//   v_h : (b,h,n,d)
//   agent, agent_v : (b,h,a,d) plane 49*64=3136
//   bias1[h][a][n], bias2[h][n][a]

// ---------------------------------------------------------------- bias precompute
__device__ __forceinline__ float bil7to14(const float* __restrict__ p, int y, int x) {
  // jax.image.resize 'bilinear' 7->14: half-pixel centers, edge-renormalized ==
  // clamped linear interp at src = i*0.5 - 0.25
  float fy = y * 0.5f - 0.25f, fx = x * 0.5f - 0.25f;
  int y0 = (int)floorf(fy); float ty = fy - (float)y0;
  int x0 = (int)floorf(fx); float tx = fx - (float)x0;
  int y0c = min(6, max(0, y0)), y1c = min(6, max(0, y0 + 1));
  int x0c = min(6, max(0, x0)), x1c = min(6, max(0, x0 + 1));
  float top = (1.f - tx) * p[y0c * 7 + x0c] + tx * p[y0c * 7 + x1c];
  float bot = (1.f - tx) * p[y1c * 7 + x0c] + tx * p[y1c * 7 + x1c];
  return (1.f - ty) * top + ty * bot;
}

__global__ __launch_bounds__(256) void make_bias_kernel(
    const float* __restrict__ an, const float* __restrict__ na,
    const float* __restrict__ ahb, const float* __restrict__ awb,
    const float* __restrict__ hab, const float* __restrict__ wab,
    float* __restrict__ bias1, float* __restrict__ bias2) {
  int ha = blockIdx.x;          // h*49 + a
  int n = threadIdx.x;
  if (n >= 196) return;
  int h = ha / 49, a = ha % 49;
  int y = n / 14, x = n % 14;
  float v1 = bil7to14(an + ha * 49, y, x);
  bias1[ha * 196 + n] = v1 + ahb[ha * 14 + y] + awb[ha * 14 + x];
  float v2 = bil7to14(na + ha * 49, y, x);
  bias2[(h * 196 + n) * 49 + a] = v2 + hab[(h * 14 + y) * 49 + a] + wab[(h * 14 + x) * 49 + a];
}

// ---------------------------------------------------------------- fp32 SGEMM (NT)
// C[m][j] = sum_k A[m][k] * W[j][k] + bias[j];  K = 512 fixed.
// MODE 0: scatter to q_h / k_t / v_h.   MODE 1: plain row-major out.
template <int MODE>
__global__ __launch_bounds__(256) void sgemm_nt(
    const float* __restrict__ A, const float* __restrict__ W,
    const float* __restrict__ bias, float* __restrict__ o0,
    float* __restrict__ o1, float* __restrict__ o2, int ntilesN) {
  __shared__ float As[16][132];
  __shared__ float Ws[16][132];
  int tid = threadIdx.x;
  int bx = blockIdx.x % ntilesN, by = blockIdx.x / ntilesN;
  int m0 = by * 128, j0 = bx * 128;
  int tx = tid & 15, ty = tid >> 4;
  const float* Ab = A + (size_t)m0 * 512;
  const float* Wb = W + (size_t)j0 * 512;
  int lrow = tid >> 2, lk = (tid & 3) * 4;
  float acc[8][8];
#pragma unroll
  for (int i = 0; i < 8; ++i)
#pragma unroll
    for (int j = 0; j < 8; ++j) acc[i][j] = 0.f;

  for (int kt = 0; kt < 512; kt += 16) {
    float4 av0 = *(const float4*)(Ab + (size_t)lrow * 512 + kt + lk);
    float4 av1 = *(const float4*)(Ab + (size_t)(lrow + 64) * 512 + kt + lk);
    float4 wv0 = *(const float4*)(Wb + (size_t)lrow * 512 + kt + lk);
    float4 wv1 = *(const float4*)(Wb + (size_t)(lrow + 64) * 512 + kt + lk);
    __syncthreads();
    As[lk + 0][lrow] = av0.x; As[lk + 1][lrow] = av0.y;
    As[lk + 2][lrow] = av0.z; As[lk + 3][lrow] = av0.w;
    As[lk + 0][lrow + 64] = av1.x; As[lk + 1][lrow + 64] = av1.y;
    As[lk + 2][lrow + 64] = av1.z; As[lk + 3][lrow + 64] = av1.w;
    Ws[lk + 0][lrow] = wv0.x; Ws[lk + 1][lrow] = wv0.y;
    Ws[lk + 2][lrow] = wv0.z; Ws[lk + 3][lrow] = wv0.w;
    Ws[lk + 0][lrow + 64] = wv1.x; Ws[lk + 1][lrow + 64] = wv1.y;
    Ws[lk + 2][lrow + 64] = wv1.z; Ws[lk + 3][lrow + 64] = wv1.w;
    __syncthreads();
#pragma unroll
    for (int k = 0; k < 16; ++k) {
      float4 a0 = *(const float4*)&As[k][ty * 8];
      float4 a1 = *(const float4*)&As[k][ty * 8 + 4];
      float4 b0 = *(const float4*)&Ws[k][tx * 8];
      float4 b1 = *(const float4*)&Ws[k][tx * 8 + 4];
      float ar[8] = {a0.x, a0.y, a0.z, a0.w, a1.x, a1.y, a1.z, a1.w};
      float br[8] = {b0.x, b0.y, b0.z, b0.w, b1.x, b1.y, b1.z, b1.w};
#pragma unroll
      for (int i = 0; i < 8; ++i)
#pragma unroll
        for (int j = 0; j < 8; ++j) acc[i][j] = fmaf(ar[i], br[j], acc[i][j]);
    }
  }

  float bloc[8];
#pragma unroll
  for (int j = 0; j < 8; ++j) bloc[j] = bias[j0 + tx * 8 + j];

  if (MODE == 0) {
#pragma unroll
    for (int i = 0; i < 8; ++i) {
      int gm = m0 + ty * 8 + i;
      int bb = gm / 196, nn = gm % 196;
#pragma unroll
      for (int jh = 0; jh < 2; ++jh) {
        int gj = j0 + tx * 8 + jh * 4;
        int which = gj >> 9;
        int hh = (gj >> 6) & 7;
        int d = gj & 63;
        size_t pbase = (size_t)(bb * 8 + hh) * 12544;
        float4 v;
        v.x = acc[i][jh * 4 + 0] + bloc[jh * 4 + 0];
        v.y = acc[i][jh * 4 + 1] + bloc[jh * 4 + 1];
        v.z = acc[i][jh * 4 + 2] + bloc[jh * 4 + 2];
        v.w = acc[i][jh * 4 + 3] + bloc[jh * 4 + 3];
        if (which == 0) {
          *(float4*)(o0 + pbase + nn * 64 + d) = v;
        } else if (which == 2) {
          *(float4*)(o2 + pbase + nn * 64 + d) = v;
        } else {  // k transposed: (b,h,d,n)
          float* kp = o1 + pbase + nn;
          kp[(size_t)(d + 0) * 196] = v.x;
          kp[(size_t)(d + 1) * 196] = v.y;
          kp[(size_t)(d + 2) * 196] = v.z;
          kp[(size_t)(d + 3) * 196] = v.w;
        }
      }
    }
  } else {
#pragma unroll
    for (int i = 0; i < 8; ++i) {
      int gm = m0 + ty * 8 + i;
#pragma unroll
      for (int jh = 0; jh < 2; ++jh) {
        int gj = j0 + tx * 8 + jh * 4;
        float4 v;
        v.x = acc[i][jh * 4 + 0] + bloc[jh * 4 + 0];
        v.y = acc[i][jh * 4 + 1] + bloc[jh * 4 + 1];
        v.z = acc[i][jh * 4 + 2] + bloc[jh * 4 + 2];
        v.w = acc[i][jh * 4 + 3] + bloc[jh * 4 + 3];
        *(float4*)(o0 + (size_t)gm * 512 + gj) = v;
      }
    }
  }
}

// ---------------------------------------------------------------- 2x2 mean pool of q -> agent
__global__ __launch_bounds__(256) void pool_kernel(const float* __restrict__ q_h,
                                                   float* __restrict__ agent) {
  int idx = blockIdx.x * 256 + threadIdx.x;  // (bh, a, d4): 4096*49*16
  int d4 = idx & 15;
  int a = (idx >> 4) % 49;
  int bh = idx / (49 * 16);
  int y1 = a / 7, x1 = a % 7;
  const float* qp = q_h + (size_t)bh * 12544;
  float sx = 0, sy = 0, sz = 0, sw = 0;
#pragma unroll
  for (int dy = 0; dy < 2; ++dy)
#pragma unroll
    for (int dx = 0; dx < 2; ++dx) {
      int nn = (2 * y1 + dy) * 14 + (2 * x1 + dx);
      float4 v = *(const float4*)(qp + nn * 64 + d4 * 4);
      sx += v.x; sy += v.y; sz += v.z; sw += v.w;
    }
  float4 r;
  r.x = sx * 0.25f; r.y = sy * 0.25f; r.z = sz * 0.25f; r.w = sw * 0.25f;
  *(float4*)(agent + (size_t)bh * 3136 + a * 64 + d4 * 4) = r;
}

// ---------------------------------------------------------------- stage 1: agent -> kv attention
__global__ __launch_bounds__(256) void stage1_kernel(
    const float* __restrict__ agent, const float* __restrict__ k_t,
    const float* __restrict__ v_h, const float* __restrict__ bias1,
    float* __restrict__ agent_v) {
  __shared__ float ah_s[49 * 64];   // agent*scale, a-major
  __shared__ float p_s[49 * 196];   // attn probs
  int bh = blockIdx.x;
  int h = bh & 7;
  int tid = threadIdx.x;
  int w = tid >> 6, lane = tid & 63;
  for (int i = tid; i < 49 * 64; i += 256)
    ah_s[i] = agent[(size_t)bh * 3136 + i] * 0.125f;
  __syncthreads();

  // scores: wave w owns rows a = w, w+4, ...; lane covers n = lane + 64*nb
  const float* kb = k_t + (size_t)bh * 12544;
  float acc[13][4];
#pragma unroll
  for (int j = 0; j < 13; ++j) {
    acc[j][0] = 0; acc[j][1] = 0; acc[j][2] = 0; acc[j][3] = 0;
  }
  for (int d = 0; d < 64; ++d) {
    float k0 = kb[d * 196 + lane];
    float k1 = kb[d * 196 + 64 + lane];
    float k2 = kb[d * 196 + 128 + lane];
    float k3 = (lane < 4) ? kb[d * 196 + 192 + lane] : 0.f;
#pragma unroll
    for (int j = 0; j < 13; ++j) {
      int a = w + 4 * j;
      if (a < 49) {
        float av = ah_s[a * 64 + d];
        acc[j][0] = fmaf(av, k0, acc[j][0]);
        acc[j][1] = fmaf(av, k1, acc[j][1]);
        acc[j][2] = fmaf(av, k2, acc[j][2]);
        acc[j][3] = fmaf(av, k3, acc[j][3]);
      }
    }
  }
  // bias + in-wave softmax over n (196), write P to LDS
#pragma unroll
  for (int j = 0; j < 13; ++j) {
    int a = w + 4 * j;
    if (a < 49) {
      const float* bb = bias1 + (size_t)(h * 49 + a) * 196;
      float s0 = acc[j][0] + bb[lane];
      float s1 = acc[j][1] + bb[64 + lane];
      float s2 = acc[j][2] + bb[128 + lane];
      float s3 = (lane < 4) ? (acc[j][3] + bb[192 + lane]) : -INFINITY;
      float m = fmaxf(fmaxf(s0, s1), fmaxf(s2, s3));
#pragma unroll
      for (int s = 32; s > 0; s >>= 1) m = fmaxf(m, __shfl_xor(m, s));
      float e0 = __expf(s0 - m), e1 = __expf(s1 - m), e2 = __expf(s2 - m);
      float e3 = (lane < 4) ? __expf(s3 - m) : 0.f;
      float sum = e0 + e1 + e2 + e3;
#pragma unroll
      for (int s = 32; s > 0; s >>= 1) sum += __shfl_xor(sum, s);
      float inv = 1.f / sum;
      p_s[a * 196 + lane] = e0 * inv;
      p_s[a * 196 + 64 + lane] = e1 * inv;
      p_s[a * 196 + 128 + lane] = e2 * inv;
      if (lane < 4) p_s[a * 196 + 192 + lane] = e3 * inv;
    }
  }
  __syncthreads();
  // PV: lane = d, rows in registers, V read once per wave
  const float* vb = v_h + (size_t)bh * 12544;
  float outr[13];
#pragma unroll
  for (int j = 0; j < 13; ++j) outr[j] = 0.f;
  for (int n = 0; n < 196; ++n) {
    float v = vb[n * 64 + lane];
#pragma unroll
    for (int j = 0; j < 13; ++j) {
      int a = w + 4 * j;
      if (a < 49) outr[j] = fmaf(p_s[a * 196 + n], v, outr[j]);
    }
  }
#pragma unroll
  for (int j = 0; j < 13; ++j) {
    int a = w + 4 * j;
    if (a < 49) agent_v[(size_t)bh * 3136 + a * 64 + lane] = outr[j];
  }
}

// ---------------------------------------------------------------- stage 2: q -> agent attention
__device__ __forceinline__ void softmax_row49(float sc, int n, int h, int lane,
                                              const float* __restrict__ bias2,
                                              float* __restrict__ p_s) {
  sc *= 0.125f;
  if (lane < 49)
    sc += bias2[((size_t)h * 196 + n) * 49 + lane];
  else
    sc = -INFINITY;
  float m = sc;
#pragma unroll
  for (int s = 32; s > 0; s >>= 1) m = fmaxf(m, __shfl_xor(m, s));
  float e = (lane < 49) ? __expf(sc - m) : 0.f;
  float sum = e;
#pragma unroll
  for (int s = 32; s > 0; s >>= 1) sum += __shfl_xor(sum, s);
  if (lane < 49) p_s[n * 49 + lane] = e / sum;
}

__global__ __launch_bounds__(256) void stage2_kernel(
    const float* __restrict__ q_h, const float* __restrict__ agent,
    const float* __restrict__ agent_v, const float* __restrict__ bias2,
    float* __restrict__ attn) {
  __shared__ float ah_t[64 * 49];   // agent transposed (d-major)
  __shared__ float av_s[49 * 64];   // agent_v a-major
  __shared__ float p_s[196 * 49];
  int bh = blockIdx.x;
  int b = bh >> 3, h = bh & 7;
  int tid = threadIdx.x;
  int w = tid >> 6, lane = tid & 63;
  for (int i = tid; i < 3136; i += 256) {
    int a = i >> 6, d = i & 63;
    ah_t[d * 49 + a] = agent[(size_t)bh * 3136 + i];
    av_s[i] = agent_v[(size_t)bh * 3136 + i];
  }
  __syncthreads();

  const float* qb = q_h + (size_t)bh * 12544;
  int al = (lane < 49) ? lane : 48;
  // scores: wave owns 49 n-rows (w*49 .. w*49+48), lane = a
  for (int g = 0; g < 12; ++g) {
    int n0 = w * 49 + g * 4;
    float s[4] = {0, 0, 0, 0};
    for (int d = 0; d < 64; ++d) {
      float av = ah_t[d * 49 + al];
      s[0] = fmaf(qb[(n0 + 0) * 64 + d], av, s[0]);
      s[1] = fmaf(qb[(n0 + 1) * 64 + d], av, s[1]);
      s[2] = fmaf(qb[(n0 + 2) * 64 + d], av, s[2]);
      s[3] = fmaf(qb[(n0 + 3) * 64 + d], av, s[3]);
    }
#pragma unroll
    for (int i = 0; i < 4; ++i) softmax_row49(s[i], n0 + i, h, lane, bias2, p_s);
  }
  {  // tail row (48th of this wave)
    int n0 = w * 49 + 48;
    float s0 = 0;
    for (int d = 0; d < 64; ++d) s0 = fmaf(qb[n0 * 64 + d], ah_t[d * 49 + al], s0);
    softmax_row49(s0, n0, h, lane, bias2, p_s);
  }
  __syncthreads();
  // PV: lane = d
  float* ob = attn + ((size_t)b * 196) * 512 + h * 64;
  for (int g = 0; g < 12; ++g) {
    int n0 = w * 49 + g * 4;
    float o[4] = {0, 0, 0, 0};
    for (int a = 0; a < 49; ++a) {
      float av = av_s[a * 64 + lane];
      o[0] = fmaf(p_s[(n0 + 0) * 49 + a], av, o[0]);
      o[1] = fmaf(p_s[(n0 + 1) * 49 + a], av, o[1]);
      o[2] = fmaf(p_s[(n0 + 2) * 49 + a], av, o[2]);
      o[3] = fmaf(p_s[(n0 + 3) * 49 + a], av, o[3]);
    }
#pragma unroll
    for (int i = 0; i < 4; ++i) ob[(size_t)(n0 + i) * 512 + lane] = o[i];
  }
  {
    int n0 = w * 49 + 48;
    float o0 = 0;
    for (int a = 0; a < 49; ++a) o0 = fmaf(p_s[n0 * 49 + a], av_s[a * 64 + lane], o0);
    ob[(size_t)n0 * 512 + lane] = o0;
  }
}

// ---------------------------------------------------------------- depthwise 3x3 conv residual
__global__ __launch_bounds__(256) void dwc_kernel(const float* __restrict__ v_h,
                                                  const float* __restrict__ w9,
                                                  const float* __restrict__ wb,
                                                  float* __restrict__ attn) {
  int idx = blockIdx.x * 256 + threadIdx.x;  // (b, n, c)
  int c = idx & 511;
  int t = idx >> 9;
  int n = t % 196, b = t / 196;
  int y = n / 14, x = n % 14;
  int h = c >> 6, d = c & 63;
  const float* vp = v_h + (size_t)(b * 8 + h) * 12544 + d;
  const float* wp = w9 + c * 9;
  float acc = wb[c];
#pragma unroll
  for (int ky = 0; ky < 3; ++ky) {
    int yy = y + ky - 1;
    if (yy < 0 || yy > 13) continue;
#pragma unroll
    for (int kx = 0; kx < 3; ++kx) {
      int xx = x + kx - 1;
      if (xx < 0 || xx > 13) continue;
      acc = fmaf(vp[(yy * 14 + xx) * 64], wp[ky * 3 + kx], acc);
    }
  }
  attn[idx] += acc;
}

// ---------------------------------------------------------------- launch
extern "C" void kernel_launch(void* const* d_in, const int* in_sizes, int n_in,
                              void* d_out, int out_size, void* d_ws, size_t ws_size,
                              hipStream_t stream) {
  const float* x      = (const float*)d_in[0];
  const float* qkv_w  = (const float*)d_in[1];
  const float* qkv_b  = (const float*)d_in[2];
  const float* proj_w = (const float*)d_in[3];
  const float* proj_b = (const float*)d_in[4];
  const float* dwc_w  = (const float*)d_in[5];
  const float* dwc_b  = (const float*)d_in[6];
  const float* an     = (const float*)d_in[7];
  const float* na     = (const float*)d_in[8];
  const float* ahb    = (const float*)d_in[9];
  const float* awb    = (const float*)d_in[10];
  const float* hab    = (const float*)d_in[11];
  const float* wab    = (const float*)d_in[12];
  float* out = (float*)d_out;

  const size_t PLANE = (size_t)4096 * 12544;   // 51,380,224 floats
  const size_t APL   = (size_t)4096 * 3136;    // 12,845,056 floats
  size_t needed = (3 * PLANE + 2 * APL + 2 * (size_t)(8 * 49 * 196)) * 4;
  if (ws_size < needed) return;  // workspace too small: fail validation loudly, don't corrupt

  float* ws      = (float*)d_ws;
  float* q_h     = ws;
  float* k_t     = q_h + PLANE;
  float* v_h     = k_t + PLANE;
  float* agent   = v_h + PLANE;
  float* agent_v = agent + APL;
  float* bias1   = agent_v + APL;
  float* bias2   = bias1 + 8 * 49 * 196;
  float* attn    = k_t;  // k dead after stage1; reuse as attn_out (b,n,c)

  make_bias_kernel<<<392, 256, 0, stream>>>(an, na, ahb, awb, hab, wab, bias1, bias2);
  sgemm_nt<0><<<784 * 12, 256, 0, stream>>>(x, qkv_w, qkv_b, q_h, k_t, v_h, 12);
  pool_kernel<<<12544, 256, 0, stream>>>(q_h, agent);
  stage1_kernel<<<4096, 256, 0, stream>>>(agent, k_t, v_h, bias1, agent_v);
  stage2_kernel<<<4096, 256, 0, stream>>>(q_h, agent, agent_v, bias2, attn);
  dwc_kernel<<<100352 * 512 / 256, 256, 0, stream>>>(v_h, dwc_w, dwc_b, attn);
  sgemm_nt<1><<<784 * 4, 256, 0, stream>>>(attn, proj_w, proj_b, out, nullptr, nullptr, 4);
}

// Round 2
// 3725.774 us; speedup vs baseline: 1.4201x; 1.4201x over previous
//
#include <hip/hip_runtime.h>
#include <math.h>

// B=512, N=196 (14x14), C=512, NH=8, HD=64, AGENT=49 (7x7)
// GEMMs: bf16x3 split MFMA (hi*hi + hi*lo + lo*hi), inputs packed IN PLACE as
// uint32 = (bf16_hi<<16)|bf16_lo. Staging via global_load_lds(16B) with an
// involutive chunk swizzle c ^= (c>>3)&7 (pre-swizzled global source, swizzled
// ds_read) to avoid 16-way LDS bank conflicts on the 128B-stride packed tile.
// ws layout identical to round 1 (719.9 MB, proven to fit).

typedef unsigned int u32;
typedef short bf16x8 __attribute__((ext_vector_type(8)));
typedef float f32x4 __attribute__((ext_vector_type(4)));

// ---------------------------------------------------------------- pack fp32 -> {bf16 hi, bf16 lo} in place
__device__ __forceinline__ u32 packsplit(float f) {
  u32 u = __float_as_uint(f);
  u32 hi = (u + 0x7FFFu + ((u >> 16) & 1u)) & 0xFFFF0000u;  // RNE bf16, kept as f32 bits
  float r = f - __uint_as_float(hi);                         // exact residual
  u32 ur = __float_as_uint(r);
  u32 lo16 = (ur + 0x7FFFu + ((ur >> 16) & 1u)) >> 16;
  return hi | (lo16 & 0xFFFFu);
}

__global__ __launch_bounds__(256) void pack_kernel(float* __restrict__ p, int n4) {
  int i = blockIdx.x * 256 + threadIdx.x;
  int stride = gridDim.x * 256;
  for (; i < n4; i += stride) {
    uint4 v = ((const uint4*)p)[i];
    uint4 r;
    r.x = packsplit(__uint_as_float(v.x));
    r.y = packsplit(__uint_as_float(v.y));
    r.z = packsplit(__uint_as_float(v.z));
    r.w = packsplit(__uint_as_float(v.w));
    ((uint4*)p)[i] = r;
  }
}

// ---------------------------------------------------------------- bias precompute (unchanged)
__device__ __forceinline__ float bil7to14(const float* __restrict__ p, int y, int x) {
  float fy = y * 0.5f - 0.25f, fx = x * 0.5f - 0.25f;
  int y0 = (int)floorf(fy); float ty = fy - (float)y0;
  int x0 = (int)floorf(fx); float tx = fx - (float)x0;
  int y0c = min(6, max(0, y0)), y1c = min(6, max(0, y0 + 1));
  int x0c = min(6, max(0, x0)), x1c = min(6, max(0, x0 + 1));
  float top = (1.f - tx) * p[y0c * 7 + x0c] + tx * p[y0c * 7 + x1c];
  float bot = (1.f - tx) * p[y1c * 7 + x0c] + tx * p[y1c * 7 + x1c];
  return (1.f - ty) * top + ty * bot;
}

__global__ __launch_bounds__(256) void make_bias_kernel(
    const float* __restrict__ an, const float* __restrict__ na,
    const float* __restrict__ ahb, const float* __restrict__ awb,
    const float* __restrict__ hab, const float* __restrict__ wab,
    float* __restrict__ bias1, float* __restrict__ bias2) {
  int ha = blockIdx.x;
  int n = threadIdx.x;
  if (n >= 196) return;
  int h = ha / 49, a = ha % 49;
  int y = n / 14, x = n % 14;
  float v1 = bil7to14(an + ha * 49, y, x);
  bias1[ha * 196 + n] = v1 + ahb[ha * 14 + y] + awb[ha * 14 + x];
  float v2 = bil7to14(na + ha * 49, y, x);
  bias2[(h * 196 + n) * 49 + a] = v2 + hab[(h * 14 + y) * 49 + a] + wab[(h * 14 + x) * 49 + a];
}

// ---------------------------------------------------------------- bf16x3 MFMA GEMM
__device__ __forceinline__ u32 prm(u32 a, u32 b, u32 sel) {
  return __builtin_amdgcn_perm(a, b, sel);
}

__device__ __forceinline__ void frag_from_packed(const u32* __restrict__ lds, int row, int kg,
                                                 bf16x8& hi, bf16x8& lo) {
  int c0 = row * 8 + kg * 2;
  int m = row & 7;
  uint4 a = *(const uint4*)(lds + ((c0 ^ m) << 2));
  uint4 b = *(const uint4*)(lds + (((c0 + 1) ^ m) << 2));
  union { uint4 u; bf16x8 v; } H, L;
  H.u.x = prm(a.y, a.x, 0x07060302u); L.u.x = prm(a.y, a.x, 0x05040100u);
  H.u.y = prm(a.w, a.z, 0x07060302u); L.u.y = prm(a.w, a.z, 0x05040100u);
  H.u.z = prm(b.y, b.x, 0x07060302u); L.u.z = prm(b.y, b.x, 0x05040100u);
  H.u.w = prm(b.w, b.z, 0x07060302u); L.u.w = prm(b.w, b.z, 0x05040100u);
  hi = H.v; lo = L.v;
}

// A: (M x 512) packed u32 row-major. W: (Nout x 512) packed u32 row-major (NT).
// MODE 0: scatter q/k_t/v.  MODE 1: row-major out.
template <int MODE>
__global__ __launch_bounds__(256) void mgemm(
    const u32* __restrict__ A, const u32* __restrict__ W,
    const float* __restrict__ bias, float* __restrict__ o0,
    float* __restrict__ o1, float* __restrict__ o2, int ntN) {
  __shared__ __align__(16) u32 Ap[4096];  // 128 rows x 32 packed k (16 KB), chunk-swizzled
  __shared__ __align__(16) u32 Wp[4096];
  int tid = threadIdx.x;
  int nwg = gridDim.x;
  int q8 = nwg >> 3;                       // nwg % 8 == 0 guaranteed by launcher
  int wg = (blockIdx.x & 7) * q8 + (blockIdx.x >> 3);  // XCD-chunked swizzle
  int bx = wg % ntN, by = wg / ntN;
  int m0 = by * 128, j0 = bx * 128;
  int w = tid >> 6, l = tid & 63;
  int wr = w >> 1, wc = w & 1;
  int lx = l & 15, ly = l >> 4;

  f32x4 acc[4][4];
#pragma unroll
  for (int i = 0; i < 4; ++i)
#pragma unroll
    for (int j = 0; j < 4; ++j) acc[i][j] = f32x4{0.f, 0.f, 0.f, 0.f};

  for (int kt = 0; kt < 16; ++kt) {
    int k0 = kt * 32;
    __syncthreads();  // previous tile fully consumed
#pragma unroll
    for (int i = 0; i < 4; ++i) {
      int s = (w * 4 + i) * 64 + l;        // LDS 16B-chunk slot
      int c = s ^ ((s >> 3) & 7);          // source chunk (involution)
      const u32* ga = A + (size_t)(m0 + (c >> 3)) * 512 + k0 + (c & 7) * 4;
      __builtin_amdgcn_global_load_lds(
          (const __attribute__((address_space(1))) void*)ga,
          (__attribute__((address_space(3))) void*)(Ap + (size_t)(w * 4 + i) * 256), 16, 0, 0);
      const u32* gw = W + (size_t)(j0 + (c >> 3)) * 512 + k0 + (c & 7) * 4;
      __builtin_amdgcn_global_load_lds(
          (const __attribute__((address_space(1))) void*)gw,
          (__attribute__((address_space(3))) void*)(Wp + (size_t)(w * 4 + i) * 256), 16, 0, 0);
    }
    __syncthreads();  // compiler drains vmcnt(0) before s_barrier

    bf16x8 ah[4], al[4], bh[4], bl[4];
#pragma unroll
    for (int mi = 0; mi < 4; ++mi)
      frag_from_packed(Ap, wr * 64 + mi * 16 + lx, ly, ah[mi], al[mi]);
#pragma unroll
    for (int ni = 0; ni < 4; ++ni)
      frag_from_packed(Wp, wc * 64 + ni * 16 + lx, ly, bh[ni], bl[ni]);
#pragma unroll
    for (int mi = 0; mi < 4; ++mi)
#pragma unroll
      for (int ni = 0; ni < 4; ++ni) {
        acc[mi][ni] = __builtin_amdgcn_mfma_f32_16x16x32_bf16(ah[mi], bh[ni], acc[mi][ni], 0, 0, 0);
        acc[mi][ni] = __builtin_amdgcn_mfma_f32_16x16x32_bf16(ah[mi], bl[ni], acc[mi][ni], 0, 0, 0);
        acc[mi][ni] = __builtin_amdgcn_mfma_f32_16x16x32_bf16(al[mi], bh[ni], acc[mi][ni], 0, 0, 0);
      }
  }

  // epilogue: C/D layout col=lane&15, row=(lane>>4)*4+r  [m89-verified]
#pragma unroll
  for (int ni = 0; ni < 4; ++ni) {
    int gj = j0 + wc * 64 + ni * 16 + lx;
    float bv = bias[gj];
    if (MODE == 1) {
#pragma unroll
      for (int mi = 0; mi < 4; ++mi)
#pragma unroll
        for (int r = 0; r < 4; ++r) {
          int gm = m0 + wr * 64 + mi * 16 + ly * 4 + r;
          o0[(size_t)gm * 512 + gj] = acc[mi][ni][r] + bv;
        }
    } else {
      int which = gj >> 9, hh = (gj >> 6) & 7, d = gj & 63;
#pragma unroll
      for (int mi = 0; mi < 4; ++mi)
#pragma unroll
        for (int r = 0; r < 4; ++r) {
          int gm = m0 + wr * 64 + mi * 16 + ly * 4 + r;
          int bb = gm / 196, nn = gm - bb * 196;
          size_t pbase = (size_t)(bb * 8 + hh) * 12544;
          float val = acc[mi][ni][r] + bv;
          if (which == 0) o0[pbase + nn * 64 + d] = val;
          else if (which == 1) o1[pbase + (size_t)d * 196 + nn] = val;  // k transposed (b,h,d,n)
          else o2[pbase + nn * 64 + d] = val;
        }
    }
  }
}

// ---------------------------------------------------------------- 2x2 mean pool of q -> agent
__global__ __launch_bounds__(256) void pool_kernel(const float* __restrict__ q_h,
                                                   float* __restrict__ agent) {
  int idx = blockIdx.x * 256 + threadIdx.x;
  int d4 = idx & 15;
  int a = (idx >> 4) % 49;
  int bh = idx / (49 * 16);
  int y1 = a / 7, x1 = a % 7;
  const float* qp = q_h + (size_t)bh * 12544;
  float sx = 0, sy = 0, sz = 0, sw = 0;
#pragma unroll
  for (int dy = 0; dy < 2; ++dy)
#pragma unroll
    for (int dx = 0; dx < 2; ++dx) {
      int nn = (2 * y1 + dy) * 14 + (2 * x1 + dx);
      float4 v = *(const float4*)(qp + nn * 64 + d4 * 4);
      sx += v.x; sy += v.y; sz += v.z; sw += v.w;
    }
  float4 r;
  r.x = sx * 0.25f; r.y = sy * 0.25f; r.z = sz * 0.25f; r.w = sw * 0.25f;
  *(float4*)(agent + (size_t)bh * 3136 + a * 64 + d4 * 4) = r;
}

// ---------------------------------------------------------------- stage 1 (unchanged)
__global__ __launch_bounds__(256) void stage1_kernel(
    const float* __restrict__ agent, const float* __restrict__ k_t,
    const float* __restrict__ v_h, const float* __restrict__ bias1,
    float* __restrict__ agent_v) {
  __shared__ float ah_s[49 * 64];
  __shared__ float p_s[49 * 196];
  int bh = blockIdx.x;
  int h = bh & 7;
  int tid = threadIdx.x;
  int w = tid >> 6, lane = tid & 63;
  for (int i = tid; i < 49 * 64; i += 256)
    ah_s[i] = agent[(size_t)bh * 3136 + i] * 0.125f;
  __syncthreads();

  const float* kb = k_t + (size_t)bh * 12544;
  float acc[13][4];
#pragma unroll
  for (int j = 0; j < 13; ++j) {
    acc[j][0] = 0; acc[j][1] = 0; acc[j][2] = 0; acc[j][3] = 0;
  }
  for (int d = 0; d < 64; ++d) {
    float k0 = kb[d * 196 + lane];
    float k1 = kb[d * 196 + 64 + lane];
    float k2 = kb[d * 196 + 128 + lane];
    float k3 = (lane < 4) ? kb[d * 196 + 192 + lane] : 0.f;
#pragma unroll
    for (int j = 0; j < 13; ++j) {
      int a = w + 4 * j;
      if (a < 49) {
        float av = ah_s[a * 64 + d];
        acc[j][0] = fmaf(av, k0, acc[j][0]);
        acc[j][1] = fmaf(av, k1, acc[j][1]);
        acc[j][2] = fmaf(av, k2, acc[j][2]);
        acc[j][3] = fmaf(av, k3, acc[j][3]);
      }
    }
  }
#pragma unroll
  for (int j = 0; j < 13; ++j) {
    int a = w + 4 * j;
    if (a < 49) {
      const float* bb = bias1 + (size_t)(h * 49 + a) * 196;
      float s0 = acc[j][0] + bb[lane];
      float s1 = acc[j][1] + bb[64 + lane];
      float s2 = acc[j][2] + bb[128 + lane];
      float s3 = (lane < 4) ? (acc[j][3] + bb[192 + lane]) : -INFINITY;
      float m = fmaxf(fmaxf(s0, s1), fmaxf(s2, s3));
#pragma unroll
      for (int s = 32; s > 0; s >>= 1) m = fmaxf(m, __shfl_xor(m, s));
      float e0 = __expf(s0 - m), e1 = __expf(s1 - m), e2 = __expf(s2 - m);
      float e3 = (lane < 4) ? __expf(s3 - m) : 0.f;
      float sum = e0 + e1 + e2 + e3;
#pragma unroll
      for (int s = 32; s > 0; s >>= 1) sum += __shfl_xor(sum, s);
      float inv = 1.f / sum;
      p_s[a * 196 + lane] = e0 * inv;
      p_s[a * 196 + 64 + lane] = e1 * inv;
      p_s[a * 196 + 128 + lane] = e2 * inv;
      if (lane < 4) p_s[a * 196 + 192 + lane] = e3 * inv;
    }
  }
  __syncthreads();
  const float* vb = v_h + (size_t)bh * 12544;
  float outr[13];
#pragma unroll
  for (int j = 0; j < 13; ++j) outr[j] = 0.f;
  for (int n = 0; n < 196; ++n) {
    float v = vb[n * 64 + lane];
#pragma unroll
    for (int j = 0; j < 13; ++j) {
      int a = w + 4 * j;
      if (a < 49) outr[j] = fmaf(p_s[a * 196 + n], v, outr[j]);
    }
  }
#pragma unroll
  for (int j = 0; j < 13; ++j) {
    int a = w + 4 * j;
    if (a < 49) agent_v[(size_t)bh * 3136 + a * 64 + lane] = outr[j];
  }
}

// ---------------------------------------------------------------- stage 2 (unchanged)
__device__ __forceinline__ void softmax_row49(float sc, int n, int h, int lane,
                                              const float* __restrict__ bias2,
                                              float* __restrict__ p_s) {
  sc *= 0.125f;
  if (lane < 49)
    sc += bias2[((size_t)h * 196 + n) * 49 + lane];
  else
    sc = -INFINITY;
  float m = sc;
#pragma unroll
  for (int s = 32; s > 0; s >>= 1) m = fmaxf(m, __shfl_xor(m, s));
  float e = (lane < 49) ? __expf(sc - m) : 0.f;
  float sum = e;
#pragma unroll
  for (int s = 32; s > 0; s >>= 1) sum += __shfl_xor(sum, s);
  if (lane < 49) p_s[n * 49 + lane] = e / sum;
}

__global__ __launch_bounds__(256) void stage2_kernel(
    const float* __restrict__ q_h, const float* __restrict__ agent,
    const float* __restrict__ agent_v, const float* __restrict__ bias2,
    float* __restrict__ attn) {
  __shared__ float ah_t[64 * 49];
  __shared__ float av_s[49 * 64];
  __shared__ float p_s[196 * 49];
  int bh = blockIdx.x;
  int b = bh >> 3, h = bh & 7;
  int tid = threadIdx.x;
  int w = tid >> 6, lane = tid & 63;
  for (int i = tid; i < 3136; i += 256) {
    int a = i >> 6, d = i & 63;
    ah_t[d * 49 + a] = agent[(size_t)bh * 3136 + i];
    av_s[i] = agent_v[(size_t)bh * 3136 + i];
  }
  __syncthreads();

  const float* qb = q_h + (size_t)bh * 12544;
  int al = (lane < 49) ? lane : 48;
  for (int g = 0; g < 12; ++g) {
    int n0 = w * 49 + g * 4;
    float s[4] = {0, 0, 0, 0};
    for (int d = 0; d < 64; ++d) {
      float av = ah_t[d * 49 + al];
      s[0] = fmaf(qb[(n0 + 0) * 64 + d], av, s[0]);
      s[1] = fmaf(qb[(n0 + 1) * 64 + d], av, s[1]);
      s[2] = fmaf(qb[(n0 + 2) * 64 + d], av, s[2]);
      s[3] = fmaf(qb[(n0 + 3) * 64 + d], av, s[3]);
    }
#pragma unroll
    for (int i = 0; i < 4; ++i) softmax_row49(s[i], n0 + i, h, lane, bias2, p_s);
  }
  {
    int n0 = w * 49 + 48;
    float s0 = 0;
    for (int d = 0; d < 64; ++d) s0 = fmaf(qb[n0 * 64 + d], ah_t[d * 49 + al], s0);
    softmax_row49(s0, n0, h, lane, bias2, p_s);
  }
  __syncthreads();
  float* ob = attn + ((size_t)b * 196) * 512 + h * 64;
  for (int g = 0; g < 12; ++g) {
    int n0 = w * 49 + g * 4;
    float o[4] = {0, 0, 0, 0};
    for (int a = 0; a < 49; ++a) {
      float av = av_s[a * 64 + lane];
      o[0] = fmaf(p_s[(n0 + 0) * 49 + a], av, o[0]);
      o[1] = fmaf(p_s[(n0 + 1) * 49 + a], av, o[1]);
      o[2] = fmaf(p_s[(n0 + 2) * 49 + a], av, o[2]);
      o[3] = fmaf(p_s[(n0 + 3) * 49 + a], av, o[3]);
    }
#pragma unroll
    for (int i = 0; i < 4; ++i) ob[(size_t)(n0 + i) * 512 + lane] = o[i];
  }
  {
    int n0 = w * 49 + 48;
    float o0 = 0;
    for (int a = 0; a < 49; ++a) o0 = fmaf(p_s[n0 * 49 + a], av_s[a * 64 + lane], o0);
    ob[(size_t)n0 * 512 + lane] = o0;
  }
}

// ---------------------------------------------------------------- depthwise 3x3 conv residual (unchanged)
__global__ __launch_bounds__(256) void dwc_kernel(const float* __restrict__ v_h,
                                                  const float* __restrict__ w9,
                                                  const float* __restrict__ wb,
                                                  float* __restrict__ attn) {
  int idx = blockIdx.x * 256 + threadIdx.x;
  int c = idx & 511;
  int t = idx >> 9;
  int n = t % 196, b = t / 196;
  int y = n / 14, x = n % 14;
  int h = c >> 6, d = c & 63;
  const float* vp = v_h + (size_t)(b * 8 + h) * 12544 + d;
  const float* wp = w9 + c * 9;
  float acc = wb[c];
#pragma unroll
  for (int ky = 0; ky < 3; ++ky) {
    int yy = y + ky - 1;
    if (yy < 0 || yy > 13) continue;
#pragma unroll
    for (int kx = 0; kx < 3; ++kx) {
      int xx = x + kx - 1;
      if (xx < 0 || xx > 13) continue;
      acc = fmaf(vp[(yy * 14 + xx) * 64], wp[ky * 3 + kx], acc);
    }
  }
  attn[idx] += acc;
}

// ---------------------------------------------------------------- launch
extern "C" void kernel_launch(void* const* d_in, const int* in_sizes, int n_in,
                              void* d_out, int out_size, void* d_ws, size_t ws_size,
                              hipStream_t stream) {
  float* x      = (float*)d_in[0];   // packed in place (harness restores inputs per replay)
  float* qkv_w  = (float*)d_in[1];
  const float* qkv_b  = (const float*)d_in[2];
  float* proj_w = (float*)d_in[3];
  const float* proj_b = (const float*)d_in[4];
  const float* dwc_w  = (const float*)d_in[5];
  const float* dwc_b  = (const float*)d_in[6];
  const float* an     = (const float*)d_in[7];
  const float* na     = (const float*)d_in[8];
  const float* ahb    = (const float*)d_in[9];
  const float* awb    = (const float*)d_in[10];
  const float* hab    = (const float*)d_in[11];
  const float* wab    = (const float*)d_in[12];
  float* out = (float*)d_out;

  const size_t PLANE = (size_t)4096 * 12544;
  const size_t APL   = (size_t)4096 * 3136;
  size_t needed = (3 * PLANE + 2 * APL + 2 * (size_t)(8 * 49 * 196)) * 4;
  if (ws_size < needed) return;

  float* ws      = (float*)d_ws;
  float* q_h     = ws;
  float* k_t     = q_h + PLANE;
  float* v_h     = k_t + PLANE;
  float* agent   = v_h + PLANE;
  float* agent_v = agent + APL;
  float* bias1   = agent_v + APL;
  float* bias2   = bias1 + 8 * 49 * 196;
  float* attn    = k_t;  // k dead after stage1

  make_bias_kernel<<<392, 256, 0, stream>>>(an, na, ahb, awb, hab, wab, bias1, bias2);
  pack_kernel<<<2048, 256, 0, stream>>>(x, 12845056);
  pack_kernel<<<768, 256, 0, stream>>>(qkv_w, 196608);
  pack_kernel<<<256, 256, 0, stream>>>(proj_w, 65536);
  mgemm<0><<<784 * 12, 256, 0, stream>>>((const u32*)x, (const u32*)qkv_w, qkv_b,
                                         q_h, k_t, v_h, 12);
  pool_kernel<<<12544, 256, 0, stream>>>(q_h, agent);
  stage1_kernel<<<4096, 256, 0, stream>>>(agent, k_t, v_h, bias1, agent_v);
  stage2_kernel<<<4096, 256, 0, stream>>>(q_h, agent, agent_v, bias2, attn);
  dwc_kernel<<<200704, 256, 0, stream>>>(v_h, dwc_w, dwc_b, attn);
  pack_kernel<<<2048, 256, 0, stream>>>(attn, 12845056);
  mgemm<1><<<784 * 4, 256, 0, stream>>>((const u32*)attn, (const u32*)proj_w, proj_b,
                                        out, nullptr, nullptr, 4);
}

// Round 3
// 2151.571 us; speedup vs baseline: 2.4592x; 1.7317x over previous
//
#include <hip/hip_runtime.h>
#include <math.h>

// B=512, N=196 (14x14), C=512, NH=8, HD=64, AGENT=49 (7x7)
// Everything numeric flows as packed-split u32 = (bf16_hi<<16)|bf16_lo; GEMM-shaped
// compute uses bf16x3 MFMA (hi*hi + hi*lo + lo*hi ~ fp32 accuracy).
// ws: bias1, bias2, q(n,d), k(n,d)->attn(f32), agent(a,d), agent_vT(d,a pad64)
// d_out doubles as vT(d,n) scratch until the final proj GEMM overwrites it.

typedef unsigned int u32;
typedef short bf16x8 __attribute__((ext_vector_type(8)));
typedef float f32x4 __attribute__((ext_vector_type(4)));

#define MFMA16 __builtin_amdgcn_mfma_f32_16x16x32_bf16

// ---------------------------------------------------------------- pack/unpack helpers
__device__ __forceinline__ u32 packsplit(float f) {
  u32 u = __float_as_uint(f);
  u32 hi = (u + 0x7FFFu + ((u >> 16) & 1u)) & 0xFFFF0000u;  // RNE bf16 (as f32 bits)
  float r = f - __uint_as_float(hi);                         // exact residual
  u32 ur = __float_as_uint(r);
  u32 lo16 = (ur + 0x7FFFu + ((ur >> 16) & 1u)) >> 16;
  return hi | (lo16 & 0xFFFFu);
}
__device__ __forceinline__ float un(u32 u) {
  return __uint_as_float(u & 0xFFFF0000u) + __uint_as_float(u << 16);
}
__device__ __forceinline__ u32 prm(u32 a, u32 b, u32 sel) {
  return __builtin_amdgcn_perm(a, b, sel);
}
// 8 consecutive packed k-values (two uint4) -> hi/lo bf16x8 fragments
__device__ __forceinline__ void unpack8(uint4 a, uint4 b, bf16x8& hi, bf16x8& lo) {
  union { uint4 u; bf16x8 v; } H, L;
  H.u.x = prm(a.y, a.x, 0x07060302u); L.u.x = prm(a.y, a.x, 0x05040100u);
  H.u.y = prm(a.w, a.z, 0x07060302u); L.u.y = prm(a.w, a.z, 0x05040100u);
  H.u.z = prm(b.y, b.x, 0x07060302u); L.u.z = prm(b.y, b.x, 0x05040100u);
  H.u.w = prm(b.w, b.z, 0x07060302u); L.u.w = prm(b.w, b.z, 0x05040100u);
  hi = H.v; lo = L.v;
}

__global__ __launch_bounds__(256) void pack_kernel(float* __restrict__ p, int n4) {
  int i = blockIdx.x * 256 + threadIdx.x;
  int stride = gridDim.x * 256;
  for (; i < n4; i += stride) {
    uint4 v = ((const uint4*)p)[i];
    uint4 r;
    r.x = packsplit(__uint_as_float(v.x));
    r.y = packsplit(__uint_as_float(v.y));
    r.z = packsplit(__uint_as_float(v.z));
    r.w = packsplit(__uint_as_float(v.w));
    ((uint4*)p)[i] = r;
  }
}

// ---------------------------------------------------------------- bias precompute
__device__ __forceinline__ float bil7to14(const float* __restrict__ p, int y, int x) {
  float fy = y * 0.5f - 0.25f, fx = x * 0.5f - 0.25f;
  int y0 = (int)floorf(fy); float ty = fy - (float)y0;
  int x0 = (int)floorf(fx); float tx = fx - (float)x0;
  int y0c = min(6, max(0, y0)), y1c = min(6, max(0, y0 + 1));
  int x0c = min(6, max(0, x0)), x1c = min(6, max(0, x0 + 1));
  float top = (1.f - tx) * p[y0c * 7 + x0c] + tx * p[y0c * 7 + x1c];
  float bot = (1.f - tx) * p[y1c * 7 + x0c] + tx * p[y1c * 7 + x1c];
  return (1.f - ty) * top + ty * bot;
}

__global__ __launch_bounds__(256) void make_bias_kernel(
    const float* __restrict__ an, const float* __restrict__ na,
    const float* __restrict__ ahb, const float* __restrict__ awb,
    const float* __restrict__ hab, const float* __restrict__ wab,
    float* __restrict__ bias1, float* __restrict__ bias2) {
  int ha = blockIdx.x;
  int n = threadIdx.x;
  if (n >= 196) return;
  int h = ha / 49, a = ha % 49;
  int y = n / 14, x = n % 14;
  float v1 = bil7to14(an + ha * 49, y, x);
  bias1[ha * 196 + n] = v1 + ahb[ha * 14 + y] + awb[ha * 14 + x];
  float v2 = bil7to14(na + ha * 49, y, x);
  bias2[(h * 196 + n) * 49 + a] = v2 + hab[(h * 14 + y) * 49 + a] + wab[(h * 14 + x) * 49 + a];
}

// ---------------------------------------------------------------- bf16x3 MFMA GEMM (validated structure)
__device__ __forceinline__ void frag_from_packed(const u32* __restrict__ lds, int row, int kg,
                                                 bf16x8& hi, bf16x8& lo) {
  int c0 = row * 8 + kg * 2;
  int m = row & 7;
  uint4 a = *(const uint4*)(lds + ((c0 ^ m) << 2));
  uint4 b = *(const uint4*)(lds + (((c0 + 1) ^ m) << 2));
  unpack8(a, b, hi, lo);
}

// MODE 0: scatter packed q(n,d)/k(n,d)/vT(d,n).  MODE 1: row-major f32 out.
template <int MODE>
__global__ __launch_bounds__(256) void mgemm(
    const u32* __restrict__ A, const u32* __restrict__ W,
    const float* __restrict__ bias, u32* __restrict__ o0,
    u32* __restrict__ o1, u32* __restrict__ o2, float* __restrict__ f0, int ntN) {
  __shared__ __align__(16) u32 Ap[4096];
  __shared__ __align__(16) u32 Wp[4096];
  int tid = threadIdx.x;
  int nwg = gridDim.x;
  int q8 = nwg >> 3;
  int wg = (blockIdx.x & 7) * q8 + (blockIdx.x >> 3);
  int bx = wg % ntN, by = wg / ntN;
  int m0 = by * 128, j0 = bx * 128;
  int w = tid >> 6, l = tid & 63;
  int wr = w >> 1, wc = w & 1;
  int lx = l & 15, ly = l >> 4;

  f32x4 acc[4][4];
#pragma unroll
  for (int i = 0; i < 4; ++i)
#pragma unroll
    for (int j = 0; j < 4; ++j) acc[i][j] = f32x4{0.f, 0.f, 0.f, 0.f};

  for (int kt = 0; kt < 16; ++kt) {
    int k0 = kt * 32;
    __syncthreads();
#pragma unroll
    for (int i = 0; i < 4; ++i) {
      int s = (w * 4 + i) * 64 + l;
      int c = s ^ ((s >> 3) & 7);
      const u32* ga = A + (size_t)(m0 + (c >> 3)) * 512 + k0 + (c & 7) * 4;
      __builtin_amdgcn_global_load_lds(
          (const __attribute__((address_space(1))) void*)ga,
          (__attribute__((address_space(3))) void*)(Ap + (size_t)(w * 4 + i) * 256), 16, 0, 0);
      const u32* gw = W + (size_t)(j0 + (c >> 3)) * 512 + k0 + (c & 7) * 4;
      __builtin_amdgcn_global_load_lds(
          (const __attribute__((address_space(1))) void*)gw,
          (__attribute__((address_space(3))) void*)(Wp + (size_t)(w * 4 + i) * 256), 16, 0, 0);
    }
    __syncthreads();

    bf16x8 ah[4], al[4], bh[4], bl[4];
#pragma unroll
    for (int mi = 0; mi < 4; ++mi)
      frag_from_packed(Ap, wr * 64 + mi * 16 + lx, ly, ah[mi], al[mi]);
#pragma unroll
    for (int ni = 0; ni < 4; ++ni)
      frag_from_packed(Wp, wc * 64 + ni * 16 + lx, ly, bh[ni], bl[ni]);
#pragma unroll
    for (int mi = 0; mi < 4; ++mi)
#pragma unroll
      for (int ni = 0; ni < 4; ++ni) {
        acc[mi][ni] = MFMA16(ah[mi], bh[ni], acc[mi][ni], 0, 0, 0);
        acc[mi][ni] = MFMA16(ah[mi], bl[ni], acc[mi][ni], 0, 0, 0);
        acc[mi][ni] = MFMA16(al[mi], bh[ni], acc[mi][ni], 0, 0, 0);
      }
  }

#pragma unroll
  for (int ni = 0; ni < 4; ++ni) {
    int gj = j0 + wc * 64 + ni * 16 + lx;
    float bv = bias[gj];
    if (MODE == 1) {
#pragma unroll
      for (int mi = 0; mi < 4; ++mi)
#pragma unroll
        for (int r = 0; r < 4; ++r) {
          int gm = m0 + wr * 64 + mi * 16 + ly * 4 + r;
          f0[(size_t)gm * 512 + gj] = acc[mi][ni][r] + bv;
        }
    } else {
      int which = gj >> 9, hh = (gj >> 6) & 7, d = gj & 63;
#pragma unroll
      for (int mi = 0; mi < 4; ++mi)
#pragma unroll
        for (int r = 0; r < 4; ++r) {
          int gm = m0 + wr * 64 + mi * 16 + ly * 4 + r;
          int bb = gm / 196, nn = gm - bb * 196;
          size_t pbase = (size_t)(bb * 8 + hh) * 12544;
          u32 pv_ = packsplit(acc[mi][ni][r] + bv);
          if (which == 0) o0[pbase + nn * 64 + d] = pv_;
          else if (which == 1) o1[pbase + nn * 64 + d] = pv_;
          else o2[pbase + (size_t)d * 196 + nn] = pv_;   // vT (d,n)
        }
    }
  }
}

// ---------------------------------------------------------------- 2x2 mean pool (packed, scale folded)
__global__ __launch_bounds__(256) void pool_kernel(const u32* __restrict__ q,
                                                   u32* __restrict__ agent) {
  int idx = blockIdx.x * 256 + threadIdx.x;  // (bh, a, d4): 4096*49*16
  int d4 = idx & 15;
  int a = (idx >> 4) % 49;
  int bh = idx / (49 * 16);
  int y1 = a / 7, x1 = a % 7;
  const u32* qp = q + (size_t)bh * 12544;
  float s0 = 0, s1 = 0, s2 = 0, s3 = 0;
#pragma unroll
  for (int dy = 0; dy < 2; ++dy)
#pragma unroll
    for (int dx = 0; dx < 2; ++dx) {
      int nn = (2 * y1 + dy) * 14 + (2 * x1 + dx);
      uint4 v = *(const uint4*)(qp + nn * 64 + d4 * 4);
      s0 += un(v.x); s1 += un(v.y); s2 += un(v.z); s3 += un(v.w);
    }
  uint4 r;  // mean (0.25) * softmax scale (0.125), folded once for both stages
  r.x = packsplit(s0 * 0.03125f); r.y = packsplit(s1 * 0.03125f);
  r.z = packsplit(s2 * 0.03125f); r.w = packsplit(s3 * 0.03125f);
  *(uint4*)(agent + (size_t)bh * 3136 + a * 64 + d4 * 4) = r;
}

// ---------------------------------------------------------------- stage 1: agent -> kv attention (MFMA)
__global__ __launch_bounds__(256) void stage1_kernel(
    const u32* __restrict__ agent, const u32* __restrict__ kpl,
    const u32* __restrict__ vT, const float* __restrict__ bias1,
    u32* __restrict__ avT) {
  __shared__ __align__(16) u32 pbuf[2048];  // 4 waves x 16x32 packed P chunk
  int bh = blockIdx.x, h = bh & 7;
  int tid = threadIdx.x, w = tid >> 6, lane = tid & 63;
  int lx = lane & 15, ly = lane >> 4;
  const u32* ag = agent + (size_t)bh * 3136;
  const u32* kb = kpl + (size_t)bh * 12544;
  const u32* vb = vT + (size_t)bh * 12544;

  // A-frags: agent rows a = w*16+lx (wave 3 rows >=49 are garbage, masked later)
  bf16x8 ah[2], al_[2];
#pragma unroll
  for (int kc = 0; kc < 2; ++kc) {
    const u32* p = ag + (size_t)(w * 16 + lx) * 64 + kc * 32 + ly * 8;
    uint4 p0 = *(const uint4*)p, p1 = *(const uint4*)(p + 4);
    unpack8(p0, p1, ah[kc], al_[kc]);
  }

  f32x4 acc[13];
#pragma unroll
  for (int ni = 0; ni < 13; ++ni) acc[ni] = f32x4{0.f, 0.f, 0.f, 0.f};

#pragma unroll
  for (int ni = 0; ni < 13; ++ni)
#pragma unroll
    for (int kc = 0; kc < 2; ++kc) {
      const u32* p = kb + (size_t)(ni * 16 + lx) * 64 + kc * 32 + ly * 8;
      uint4 p0 = *(const uint4*)p, p1 = *(const uint4*)(p + 4);
      bf16x8 bh_, bl_;
      unpack8(p0, p1, bh_, bl_);
      acc[ni] = MFMA16(ah[kc], bh_, acc[ni], 0, 0, 0);
      acc[ni] = MFMA16(ah[kc], bl_, acc[ni], 0, 0, 0);
      acc[ni] = MFMA16(al_[kc], bh_, acc[ni], 0, 0, 0);
    }

  // bias + n-mask
  int a_base = w * 16 + ly * 4;
#pragma unroll
  for (int ni = 0; ni < 13; ++ni) {
    int n = ni * 16 + lx;
    bool ok = n < 196;
#pragma unroll
    for (int r = 0; r < 4; ++r) {
      float bv = bias1[(size_t)(h * 49 + a_base + r) * 196 + (ok ? n : 0)];
      acc[ni][r] = ok ? acc[ni][r] + bv : -INFINITY;
    }
  }
  // softmax over n (wave-local: 13 regs + 4-shfl within 16-lane group)
#pragma unroll
  for (int r = 0; r < 4; ++r) {
    float m = acc[0][r];
#pragma unroll
    for (int ni = 1; ni < 13; ++ni) m = fmaxf(m, acc[ni][r]);
    m = fmaxf(m, __shfl_xor(m, 1)); m = fmaxf(m, __shfl_xor(m, 2));
    m = fmaxf(m, __shfl_xor(m, 4)); m = fmaxf(m, __shfl_xor(m, 8));
    float sum = 0.f;
#pragma unroll
    for (int ni = 0; ni < 13; ++ni) {
      float e = __expf(acc[ni][r] - m);
      acc[ni][r] = e; sum += e;
    }
    sum += __shfl_xor(sum, 1); sum += __shfl_xor(sum, 2);
    sum += __shfl_xor(sum, 4); sum += __shfl_xor(sum, 8);
    float inv = 1.f / sum;
#pragma unroll
    for (int ni = 0; ni < 13; ++ni) acc[ni][r] *= inv;
  }

  // PV: per 32-col n-chunk, stage P (packed) in wave-private LDS, accumulate
  int wbase = w * 512;
  f32x4 pv[4];
#pragma unroll
  for (int nd = 0; nd < 4; ++nd) pv[nd] = f32x4{0.f, 0.f, 0.f, 0.f};
#pragma unroll
  for (int kc = 0; kc < 7; ++kc) {
#pragma unroll
    for (int hi = 0; hi < 2; ++hi) {
      int ni = kc * 2 + hi;
#pragma unroll
      for (int r = 0; r < 4; ++r) {
        float pval = 0.f;
        if (ni < 13) pval = acc[ni][r];
        int a_l = ly * 4 + r;
        int n_l = hi * 16 + lx;
        int addr = wbase + a_l * 32 + (((n_l >> 3) ^ (a_l & 3)) << 3) + (n_l & 7);
        pbuf[addr] = packsplit(pval);
      }
    }
    const u32* pp = pbuf + wbase + lx * 32 + ((ly ^ (lx & 3)) << 3);
    uint4 p0 = *(const uint4*)pp, p1 = *(const uint4*)(pp + 4);
    bf16x8 ph, pl;
    unpack8(p0, p1, ph, pl);
#pragma unroll
    for (int nd = 0; nd < 4; ++nd) {
      uint4 q0, q1;
      if (kc < 6) {
        const u32* vp = vb + (size_t)(nd * 16 + lx) * 196 + kc * 32 + ly * 8;
        q0 = *(const uint4*)vp; q1 = *(const uint4*)(vp + 4);
      } else if (ly == 0) {  // n slots 192..195 real; 196..199 multiply P==0 -> zeros
        const u32* vp = vb + (size_t)(nd * 16 + lx) * 196 + 192;
        q0 = *(const uint4*)vp; q1 = uint4{0, 0, 0, 0};
      } else {               // slots 200..223: P==0
        q0 = uint4{0, 0, 0, 0}; q1 = uint4{0, 0, 0, 0};
      }
      bf16x8 vh, vl;
      unpack8(q0, q1, vh, vl);
      pv[nd] = MFMA16(ph, vh, pv[nd], 0, 0, 0);
      pv[nd] = MFMA16(ph, vl, pv[nd], 0, 0, 0);
      pv[nd] = MFMA16(pl, vh, pv[nd], 0, 0, 0);
    }
  }
  // store agent_v transposed (d, a) stride 64, zero-padded a>=49
  u32* ob = avT + (size_t)bh * 4096;
#pragma unroll
  for (int nd = 0; nd < 4; ++nd) {
    int d = nd * 16 + lx;
#pragma unroll
    for (int r = 0; r < 4; ++r) {
      int a = w * 16 + ly * 4 + r;
      float val = (a < 49) ? pv[nd][r] : 0.f;
      ob[(size_t)d * 64 + a] = packsplit(val);
    }
  }
}

// ---------------------------------------------------------------- stage 2: q -> agent attention (MFMA)
__global__ __launch_bounds__(256) void stage2_kernel(
    const u32* __restrict__ q, const u32* __restrict__ agent,
    const u32* __restrict__ avT, const float* __restrict__ bias2,
    float* __restrict__ attn) {
  __shared__ __align__(16) u32 pbuf[4096];  // 4 waves x 16x64 packed P
  int bh = blockIdx.x, b = bh >> 3, h = bh & 7;
  int tid = threadIdx.x, w = tid >> 6, lane = tid & 63;
  int lx = lane & 15, ly = lane >> 4;
  const u32* qb = q + (size_t)bh * 12544;
  const u32* ag = agent + (size_t)bh * 3136;
  const u32* av = avT + (size_t)bh * 4096;
  float* ob = attn + (size_t)(b * 196) * 512 + h * 64;

  // agent B-frags resident in registers (shared across all M-tiles)
  bf16x8 gh[4][2], gl[4][2];
#pragma unroll
  for (int ni = 0; ni < 4; ++ni)
#pragma unroll
    for (int kc = 0; kc < 2; ++kc) {
      const u32* p = ag + (size_t)(ni * 16 + lx) * 64 + kc * 32 + ly * 8;
      uint4 p0 = *(const uint4*)p, p1 = *(const uint4*)(p + 4);
      unpack8(p0, p1, gh[ni][kc], gl[ni][kc]);
    }

  int wbase = w * 1024;
  for (int mt = w; mt < 13; mt += 4) {
    int n0 = mt * 16;
    bf16x8 ah[2], al_[2];
#pragma unroll
    for (int kc = 0; kc < 2; ++kc) {
      const u32* p = qb + (size_t)(n0 + lx) * 64 + kc * 32 + ly * 8;
      uint4 p0 = *(const uint4*)p, p1 = *(const uint4*)(p + 4);
      unpack8(p0, p1, ah[kc], al_[kc]);
    }
    f32x4 acc[4];
#pragma unroll
    for (int ni = 0; ni < 4; ++ni) acc[ni] = f32x4{0.f, 0.f, 0.f, 0.f};
#pragma unroll
    for (int kc = 0; kc < 2; ++kc)
#pragma unroll
      for (int ni = 0; ni < 4; ++ni) {
        acc[ni] = MFMA16(ah[kc], gh[ni][kc], acc[ni], 0, 0, 0);
        acc[ni] = MFMA16(ah[kc], gl[ni][kc], acc[ni], 0, 0, 0);
        acc[ni] = MFMA16(al_[kc], gh[ni][kc], acc[ni], 0, 0, 0);
      }
    // bias + a-mask + softmax over a
#pragma unroll
    for (int ni = 0; ni < 4; ++ni) {
      int a = ni * 16 + lx;
      bool ok = a < 49;
#pragma unroll
      for (int r = 0; r < 4; ++r) {
        int n = n0 + ly * 4 + r;
        int nc = n < 196 ? n : 195;
        float bv = bias2[(size_t)(h * 196 + nc) * 49 + (ok ? a : 0)];
        acc[ni][r] = ok ? acc[ni][r] + bv : -INFINITY;
      }
    }
#pragma unroll
    for (int r = 0; r < 4; ++r) {
      float m = fmaxf(fmaxf(acc[0][r], acc[1][r]), fmaxf(acc[2][r], acc[3][r]));
      m = fmaxf(m, __shfl_xor(m, 1)); m = fmaxf(m, __shfl_xor(m, 2));
      m = fmaxf(m, __shfl_xor(m, 4)); m = fmaxf(m, __shfl_xor(m, 8));
      float sum = 0.f;
#pragma unroll
      for (int ni = 0; ni < 4; ++ni) {
        float e = __expf(acc[ni][r] - m);
        acc[ni][r] = e; sum += e;
      }
      sum += __shfl_xor(sum, 1); sum += __shfl_xor(sum, 2);
      sum += __shfl_xor(sum, 4); sum += __shfl_xor(sum, 8);
      float inv = 1.f / sum;
#pragma unroll
      for (int ni = 0; ni < 4; ++ni) acc[ni][r] *= inv;
    }
    // P -> wave-private LDS (packed, XOR-swizzled at 8-u32 chunks)
#pragma unroll
    for (int ni = 0; ni < 4; ++ni) {
      int a = ni * 16 + lx;
#pragma unroll
      for (int r = 0; r < 4; ++r) {
        int n_l = ly * 4 + r;
        int addr = wbase + n_l * 64 + (((a >> 3) ^ (n_l & 7)) << 3) + (a & 7);
        pbuf[addr] = packsplit(acc[ni][r]);
      }
    }
    // PV: out(n,d) = P(n,a) @ avT(d,a)^T
    f32x4 pv[4];
#pragma unroll
    for (int nd = 0; nd < 4; ++nd) pv[nd] = f32x4{0.f, 0.f, 0.f, 0.f};
#pragma unroll
    for (int kc = 0; kc < 2; ++kc) {
      const u32* pp = pbuf + wbase + lx * 64 + ((((kc * 4 + ly) ^ (lx & 7))) << 3);
      uint4 p0 = *(const uint4*)pp, p1 = *(const uint4*)(pp + 4);
      bf16x8 ph, pl;
      unpack8(p0, p1, ph, pl);
#pragma unroll
      for (int nd = 0; nd < 4; ++nd) {
        const u32* vp = av + (size_t)(nd * 16 + lx) * 64 + kc * 32 + ly * 8;
        uint4 q0 = *(const uint4*)vp, q1 = *(const uint4*)(vp + 4);
        bf16x8 vh, vl;
        unpack8(q0, q1, vh, vl);
        pv[nd] = MFMA16(ph, vh, pv[nd], 0, 0, 0);
        pv[nd] = MFMA16(ph, vl, pv[nd], 0, 0, 0);
        pv[nd] = MFMA16(pl, vh, pv[nd], 0, 0, 0);
      }
    }
#pragma unroll
    for (int nd = 0; nd < 4; ++nd) {
      int d = nd * 16 + lx;
#pragma unroll
      for (int r = 0; r < 4; ++r) {
        int n = n0 + ly * 4 + r;
        if (n < 196) ob[(size_t)n * 512 + d] = pv[nd][r];
      }
    }
  }
}

// ---------------------------------------------------------------- depthwise 3x3 + residual add + pack
__global__ __launch_bounds__(256) void dwc_kernel(const u32* __restrict__ vT,
                                                  const float* __restrict__ w9,
                                                  const float* __restrict__ wb,
                                                  float* __restrict__ attn) {
  __shared__ float vs[64 * 197];  // [d][n] pad 197 -> conflict-free (gcd(5,32)=1)
  int bh = blockIdx.x, b = bh >> 3, h = bh & 7;
  int tid = threadIdx.x, w = tid >> 6, lane = tid & 63;
  const u32* vp = vT + (size_t)bh * 12544;
#pragma unroll
  for (int dr = 0; dr < 16; ++dr) {
    int row = w * 16 + dr;
    const u32* rp = vp + row * 196;
    float* sp = vs + row * 197;
    sp[lane] = un(rp[lane]);
    sp[lane + 64] = un(rp[lane + 64]);
    sp[lane + 128] = un(rp[lane + 128]);
    if (lane < 4) sp[lane + 192] = un(rp[lane + 192]);
  }
  __syncthreads();
  int c = h * 64 + lane;
  float wreg[9];
#pragma unroll
  for (int t = 0; t < 9; ++t) wreg[t] = w9[c * 9 + t];
  float bv = wb[c];
  float* ap = attn + (size_t)(b * 196) * 512 + c;
  const float* vrow = vs + lane * 197;
  for (int j = 0; j < 49; ++j) {
    int n = w * 49 + j;
    int y = n / 14, x = n - y * 14;
    float s = bv;
#pragma unroll
    for (int ky = 0; ky < 3; ++ky) {
      int yy = y + ky - 1;
      if (yy < 0 || yy > 13) continue;
#pragma unroll
      for (int kx = 0; kx < 3; ++kx) {
        int xx = x + kx - 1;
        if (xx < 0 || xx > 13) continue;
        s = fmaf(vrow[yy * 14 + xx], wreg[ky * 3 + kx], s);
      }
    }
    float val = ap[(size_t)n * 512] + s;
    ((u32*)ap)[(size_t)n * 512] = packsplit(val);  // pack in place for proj GEMM
  }
}

// ---------------------------------------------------------------- launch
extern "C" void kernel_launch(void* const* d_in, const int* in_sizes, int n_in,
                              void* d_out, int out_size, void* d_ws, size_t ws_size,
                              hipStream_t stream) {
  float* x      = (float*)d_in[0];   // packed in place (harness restores per replay)
  float* qkv_w  = (float*)d_in[1];
  const float* qkv_b  = (const float*)d_in[2];
  float* proj_w = (float*)d_in[3];
  const float* proj_b = (const float*)d_in[4];
  const float* dwc_w  = (const float*)d_in[5];
  const float* dwc_b  = (const float*)d_in[6];
  const float* an     = (const float*)d_in[7];
  const float* na     = (const float*)d_in[8];
  const float* ahb    = (const float*)d_in[9];
  const float* awb    = (const float*)d_in[10];
  const float* hab    = (const float*)d_in[11];
  const float* wab    = (const float*)d_in[12];
  float* out = (float*)d_out;

  const size_t PLANE = (size_t)4096 * 12544;  // 51,380,224
  const size_t BIAS  = (size_t)8 * 49 * 196;  // 76,832
  size_t needed = (2 * BIAS + 2 * PLANE + (size_t)4096 * 3136 + (size_t)4096 * 4096) * 4;
  if (ws_size < needed) return;  // ~506 MB; round-1 proved >= 719 MB available

  u32* wsu    = (u32*)d_ws;
  float* bias1 = (float*)wsu;
  float* bias2 = bias1 + BIAS;
  u32* q_h    = wsu + 2 * BIAS;
  u32* k_h    = q_h + PLANE;              // aliased as attn (f32) after stage1
  u32* agent  = k_h + PLANE;
  u32* avT    = agent + (size_t)4096 * 3136;
  u32* vT     = (u32*)d_out;              // scratch until proj GEMM writes out
  float* attn = (float*)k_h;

  make_bias_kernel<<<392, 256, 0, stream>>>(an, na, ahb, awb, hab, wab, bias1, bias2);
  pack_kernel<<<2048, 256, 0, stream>>>(x, 12845056);
  pack_kernel<<<768, 256, 0, stream>>>(qkv_w, 196608);
  pack_kernel<<<256, 256, 0, stream>>>(proj_w, 65536);
  mgemm<0><<<784 * 12, 256, 0, stream>>>((const u32*)x, (const u32*)qkv_w, qkv_b,
                                         q_h, k_h, vT, nullptr, 12);
  pool_kernel<<<12544, 256, 0, stream>>>(q_h, agent);
  stage1_kernel<<<4096, 256, 0, stream>>>(agent, k_h, vT, bias1, avT);
  stage2_kernel<<<4096, 256, 0, stream>>>(q_h, agent, avT, bias2, attn);
  dwc_kernel<<<4096, 256, 0, stream>>>(vT, dwc_w, dwc_b, attn);
  mgemm<1><<<784 * 4, 256, 0, stream>>>((const u32*)attn, (const u32*)proj_w, proj_b,
                                        nullptr, nullptr, nullptr, out, 4);
}